// Round 17
// baseline (365.698 us; speedup 1.0000x reference)
//
#include <hip/hip_runtime.h>

typedef unsigned short u16;
typedef unsigned int u32;
typedef __bf16 bf16x8 __attribute__((ext_vector_type(8)));
typedef float f32x4 __attribute__((ext_vector_type(4)));
typedef u16 u16x8 __attribute__((ext_vector_type(8)));
typedef u16 u16x4 __attribute__((ext_vector_type(4)));

typedef __attribute__((address_space(1))) const unsigned char gc_u8;
typedef __attribute__((address_space(3))) unsigned char lds_u8;

__device__ inline void gload16(const void* g, void* l) {
    __builtin_amdgcn_global_load_lds((gc_u8*)g, (lds_u8*)l, 16, 0, 0);
}
__device__ inline u16 f2bf(float f) {
    union { __bf16 h; u16 u; } c; c.h = (__bf16)f; return c.u;
}
__device__ inline float bf2f(u16 u) {
    union { u16 u[2]; float f; } c; c.u[0] = 0; c.u[1] = u; return c.f;
}
// Fully-fenced barrier: nothing (incl. register-only ops / ds ops) crosses.
__device__ inline void hard_barrier() {
    __builtin_amdgcn_sched_barrier(0);
    __builtin_amdgcn_s_barrier();
    __builtin_amdgcn_sched_barrier(0);
}
#define WAIT_LGKM0() asm volatile("s_waitcnt lgkmcnt(0)" ::: "memory")
#define WAIT_VMCNT(n) asm volatile("s_waitcnt vmcnt(" #n ")" ::: "memory")

// ---------------- weight fp32 -> bf16 convert ----------------
__global__ __launch_bounds__(256) void cvt4(const float* __restrict__ s0,
                                            const float* __restrict__ s1,
                                            const float* __restrict__ s2,
                                            const float* __restrict__ s3,
                                            u16* __restrict__ d0, u16* __restrict__ d1,
                                            u16* __restrict__ d2, u16* __restrict__ d3,
                                            int n) {
    const int y = blockIdx.y;
    const float* src = (y == 0) ? s0 : (y == 1) ? s1 : (y == 2) ? s2 : s3;
    u16* dst = (y == 0) ? d0 : (y == 1) ? d1 : (y == 2) ? d2 : d3;
    int i = (blockIdx.x * 256 + threadIdx.x) * 4;
    if (i < n) {
        float4 f = *reinterpret_cast<const float4*>(src + i);
        u16x4 u = { f2bf(f.x), f2bf(f.y), f2bf(f.z), f2bf(f.w) };
        *reinterpret_cast<u16x4*>(dst + i) = u;
    }
}

// ---------------- merged QKV projection GEMM, f32-A direct (R13/R15-proven) ----------------
__global__ __launch_bounds__(256) void gemm_qkv(const float* __restrict__ Aq,
                                                const float* __restrict__ Ak,
                                                const float* __restrict__ Av,
                                                const u16* __restrict__ Bq,
                                                const u16* __restrict__ Bk,
                                                const u16* __restrict__ Bv,
                                                const float* __restrict__ bq,
                                                const float* __restrict__ bk,
                                                const float* __restrict__ bv,
                                                const int* __restrict__ Mk,
                                                u16* __restrict__ Cq,
                                                u16* __restrict__ Ck,
                                                u16* __restrict__ Cvp,
                                                int M, int N, int K) {
    __shared__ __align__(16) float Asf[2][128][32];
    __shared__ __align__(16) u16 Bs[2][128][32];
    const int z = blockIdx.z;
    const float* A = (z == 0) ? Aq : (z == 1) ? Ak : Av;
    const u16* B = (z == 0) ? Bq : (z == 1) ? Bk : Bv;
    const float* bias = (z == 0) ? bq : (z == 1) ? bk : bv;
    u16* Cv = (z == 0) ? Cq : (z == 1) ? Ck : Cvp;
    const bool vmode = (z == 2);

    const int t = threadIdx.x, lane = t & 63, w = t >> 6;
    const int wr = w >> 1, wc = w & 1;
    const int l15 = lane & 15, l16 = lane >> 4;
    const int nwg = gridDim.x, ntiles = N >> 7;
    const int wg = blockIdx.x, chunk = nwg >> 3;
    const int swz = (wg & 7) * chunk + (wg >> 3);
    const int bm = (swz / ntiles) * 128, bn = (swz % ntiles) * 128;
    const int srow = w * 16 + (lane >> 2);
    const int sgr = (lane & 3) * 8;
    const int arsub = lane >> 3;
    const int agr = ((lane & 7) ^ (lane >> 3)) * 4;
    const u16* Bb = B + (size_t)bn * K;

    f32x4 acc[4][4];
#pragma unroll
    for (int i = 0; i < 4; i++)
#pragma unroll
        for (int j = 0; j < 4; j++) acc[i][j] = (f32x4){0.f, 0.f, 0.f, 0.f};

    auto stage = [&](int c, int k0) {
#pragma unroll
        for (int ch = 0; ch < 4; ch++)
            gload16(A + (size_t)(bm + ch * 32 + w * 8 + arsub) * K + k0 + agr,
                    &Asf[c][ch * 32 + w * 8][0]);
        gload16(Bb + (size_t)srow * K + k0 + sgr,        &Bs[c][w * 16][0]);
        gload16(Bb + (size_t)(64 + srow) * K + k0 + sgr, &Bs[c][64 + w * 16][0]);
    };

    stage(0, 0);
    __syncthreads();

    const int NS = K >> 5;
    for (int i = 0; i < NS; ++i) {
        const int c = i & 1;
        WAIT_LGKM0();
        hard_barrier();
        if (i + 1 < NS) {
            stage(c ^ 1, (i + 1) * 32);
            WAIT_VMCNT(6);
        } else {
            WAIT_VMCNT(0);
        }
        hard_barrier();

        const int key = l15 & 7;
        bf16x8 afr[4], bfr[4];
#pragma unroll
        for (int mi = 0; mi < 4; mi++) {
            const int rr = wr * 64 + mi * 16 + l15;
            f32x4 lo = *(const f32x4*)&Asf[c][rr][((2 * l16) ^ key) * 4];
            f32x4 hi = *(const f32x4*)&Asf[c][rr][((2 * l16 + 1) ^ key) * 4];
            bf16x8 v;
            v[0] = (__bf16)lo[0]; v[1] = (__bf16)lo[1];
            v[2] = (__bf16)lo[2]; v[3] = (__bf16)lo[3];
            v[4] = (__bf16)hi[0]; v[5] = (__bf16)hi[1];
            v[6] = (__bf16)hi[2]; v[7] = (__bf16)hi[3];
            afr[mi] = v;
        }
#pragma unroll
        for (int ni = 0; ni < 4; ni++)
            bfr[ni] = *(const bf16x8*)&Bs[c][wc * 64 + ni * 16 + l15][l16 * 8];
#pragma unroll
        for (int mi = 0; mi < 4; mi++)
#pragma unroll
            for (int ni = 0; ni < 4; ni++)
                acc[mi][ni] = __builtin_amdgcn_mfma_f32_16x16x32_bf16(
                    afr[mi], bfr[ni], acc[mi][ni], 0, 0, 0);
    }

#pragma unroll
    for (int ni = 0; ni < 4; ni++) {
        const int col = bn + wc * 64 + ni * 16 + l15;
        const float bv2 = bias[col];
#pragma unroll
        for (int mi = 0; mi < 4; mi++) {
            const int r0 = bm + wr * 64 + mi * 16 + l16 * 4;
            if (vmode) {
                const int bb = r0 >> 11, ss = r0 & 2047;
                const int hh = col >> 6, dk = col & 63;
                const int4 m4 = *(const int4*)&Mk[bb * 2048 + ss];
                u16x4 pk;
                pk[0] = m4.x ? f2bf(acc[mi][ni][0] + bv2) : (u16)0;
                pk[1] = m4.y ? f2bf(acc[mi][ni][1] + bv2) : (u16)0;
                pk[2] = m4.z ? f2bf(acc[mi][ni][2] + bv2) : (u16)0;
                pk[3] = m4.w ? f2bf(acc[mi][ni][3] + bv2) : (u16)0;
                *(u16x4*)&Cv[(((size_t)(bb * 16 + hh) * 64 + dk) << 11) + ss] = pk;
            } else {
#pragma unroll
                for (int r = 0; r < 4; r++)
                    Cv[(size_t)(r0 + r) * N + col] = f2bf(acc[mi][ni][r] + bv2);
            }
        }
    }
}

// ---------------- out-projection GEMM (f32 out) — UNCHANGED ----------------
__global__ __launch_bounds__(256) void gemm_out(const u16* __restrict__ A,
                                                const u16* __restrict__ B,
                                                const float* __restrict__ bias,
                                                float* __restrict__ Cv,
                                                int M, int N, int K) {
    __shared__ __align__(16) u16 As[2][128][32];
    __shared__ __align__(16) u16 Bs[2][128][32];
    const int t = threadIdx.x, lane = t & 63, w = t >> 6;
    const int wr = w >> 1, wc = w & 1;
    const int l15 = lane & 15, l16 = lane >> 4;
    const int nwg = gridDim.x, ntiles = N >> 7;
    const int wg = blockIdx.x, chunk = nwg >> 3;
    const int swz = (wg & 7) * chunk + (wg >> 3);
    const int bm = (swz / ntiles) * 128, bn = (swz % ntiles) * 128;
    const int srow = w * 16 + (lane >> 2);
    const int sgr = (lane & 3) * 8;
    const u16* Ab = A + (size_t)bm * K;
    const u16* Bb = B + (size_t)bn * K;

    f32x4 acc[4][4];
#pragma unroll
    for (int i = 0; i < 4; i++)
#pragma unroll
        for (int j = 0; j < 4; j++) acc[i][j] = (f32x4){0.f, 0.f, 0.f, 0.f};

    auto stage = [&](int c, int k0) {
        gload16(Ab + (size_t)srow * K + k0 + sgr,        &As[c][w * 16][0]);
        gload16(Ab + (size_t)(64 + srow) * K + k0 + sgr, &As[c][64 + w * 16][0]);
        gload16(Bb + (size_t)srow * K + k0 + sgr,        &Bs[c][w * 16][0]);
        gload16(Bb + (size_t)(64 + srow) * K + k0 + sgr, &Bs[c][64 + w * 16][0]);
    };

    stage(0, 0);
    __syncthreads();

    const int NS = K >> 5;
    for (int i = 0; i < NS; ++i) {
        const int c = i & 1;
        WAIT_LGKM0();
        hard_barrier();
        if (i + 1 < NS) {
            stage(c ^ 1, (i + 1) * 32);
            WAIT_VMCNT(4);
        } else {
            WAIT_VMCNT(0);
        }
        hard_barrier();

        bf16x8 afr[4], bfr[4];
#pragma unroll
        for (int mi = 0; mi < 4; mi++)
            afr[mi] = *(const bf16x8*)&As[c][wr * 64 + mi * 16 + l15][l16 * 8];
#pragma unroll
        for (int ni = 0; ni < 4; ni++)
            bfr[ni] = *(const bf16x8*)&Bs[c][wc * 64 + ni * 16 + l15][l16 * 8];
#pragma unroll
        for (int mi = 0; mi < 4; mi++)
#pragma unroll
            for (int ni = 0; ni < 4; ni++)
                acc[mi][ni] = __builtin_amdgcn_mfma_f32_16x16x32_bf16(
                    afr[mi], bfr[ni], acc[mi][ni], 0, 0, 0);
    }

#pragma unroll
    for (int ni = 0; ni < 4; ni++) {
        const int col = bn + wc * 64 + ni * 16 + l15;
        const float bv = bias[col];
#pragma unroll
        for (int mi = 0; mi < 4; mi++) {
            const int r0 = bm + wr * 64 + mi * 16 + l16 * 4;
#pragma unroll
            for (int r = 0; r < 4; r++)
                Cv[(size_t)(r0 + r) * N + col] = acc[mi][ni][r] + bv;
        }
    }
}

// ---------------- key compaction: drop masked keys (order-preserving) ----------------
// Shared helper pattern: bitmap W[64] + exclusive word-prefix Wpre in LDS.
__global__ __launch_bounds__(256) void compactK(const u16* __restrict__ Kb,
                                                u16* __restrict__ Kc,
                                                const int* __restrict__ mask) {
    __shared__ u32 W[64];
    __shared__ u32 Wpre[65];
    const int t = threadIdx.x;
    const int b = blockIdx.y, chunk = blockIdx.x;   // chunk 0..7 copy, 8 = pad-zero
    const int* mrow = mask + b * 2048;
    if (t < 64) {
        u32 wv = 0;
#pragma unroll 8
        for (int j = 0; j < 32; j++) wv |= (mrow[t * 32 + j] ? 1u : 0u) << j;
        W[t] = wv;
    }
    __syncthreads();
    if (t == 0) {
        u32 s = 0;
        for (int i = 0; i < 64; i++) { Wpre[i] = s; s += __popc(W[i]); }
        Wpre[64] = s;
    }
    __syncthreads();
    const int Nb = (int)Wpre[64];
    if (chunk == 8) {   // zero pad rows [Nb, ceil128)
        const int pad = (Nb + 127) & ~127;
        for (int r = Nb; r < pad; ++r) {
            u16x4 z = {0, 0, 0, 0};
            *(u16x4*)&Kc[((size_t)b * 2048 + r) * 1024 + t * 4] = z;
        }
        return;
    }
    const int s0 = chunk * 256;
    for (int i = 0; i < 256; ++i) {
        const int s = s0 + i;
        const u32 word = W[s >> 5];
        if ((word >> (s & 31)) & 1u) {
            const int d = (int)Wpre[s >> 5] + __popc(word & ((1u << (s & 31)) - 1u));
            *(u16x4*)&Kc[((size_t)b * 2048 + d) * 1024 + t * 4] =
                *(const u16x4*)&Kb[((size_t)b * 2048 + s) * 1024 + t * 4];
        }
    }
}

__global__ __launch_bounds__(256) void compactV(const u16* __restrict__ Vtb,
                                                u16* __restrict__ Vtc,
                                                const int* __restrict__ mask,
                                                int* __restrict__ NbA) {
    __shared__ u32 W[64];
    __shared__ u32 Wpre[65];
    const int t = threadIdx.x, lane = t & 63, w = t >> 6;
    const int h = blockIdx.x, b = blockIdx.y;
    const int* mrow = mask + b * 2048;
    if (t < 64) {
        u32 wv = 0;
#pragma unroll 8
        for (int j = 0; j < 32; j++) wv |= (mrow[t * 32 + j] ? 1u : 0u) << j;
        W[t] = wv;
    }
    __syncthreads();
    if (t == 0) {
        u32 s = 0;
        for (int i = 0; i < 64; i++) { Wpre[i] = s; s += __popc(W[i]); }
        Wpre[64] = s;
        if (h == 0) NbA[b] = (int)s;
    }
    __syncthreads();
    const int Nb = (int)Wpre[64];
    const int pad = (Nb + 127) & ~127;
    for (int dk = w; dk < 64; dk += 4) {
        const u16* src = Vtb + ((size_t)(b * 16 + h) * 64 + dk) * 2048;
        u16* dst = Vtc + ((size_t)(b * 16 + h) * 64 + dk) * 2048;
        for (int i = 0; i < 32; ++i) {
            const int s = i * 64 + lane;
            const u32 word = W[s >> 5];
            const u16 v = src[s];
            if ((word >> (s & 31)) & 1u) {
                const int d = (int)Wpre[s >> 5] + __popc(word & ((1u << (s & 31)) - 1u));
                dst[d] = v;
            }
        }
        for (int s = Nb + lane; s < pad; s += 64) dst[s] = 0;
    }
}

// ---------------- flash attention over COMPACTED keys (R15 body, variable nt) ----------------
__global__ __launch_bounds__(256, 2) void attn_fwd(const u16* __restrict__ Q,
                                                   const u16* __restrict__ Kg,
                                                   const u16* __restrict__ Vt,
                                                   const int* __restrict__ NbA,
                                                   u16* __restrict__ O) {
    constexpr int S = 2048, D = 1024;
    __shared__ __align__(16) u16 Kl[2][2][2][64][32];
    __shared__ __align__(16) u16 Vl[2][2][2][64][32];
    __shared__ __align__(16) u16 Pl[4][16][68];
    __shared__ __align__(16) u16 Ml[2048];             // validity: i < Nb
    const int t = threadIdx.x, lane = t & 63, w = t >> 6;
    const int l15 = lane & 15, l16 = lane >> 4;
    const int wg = blockIdx.x;
    const int swz = (wg & 7) * 64 + (wg >> 3);
    const int q0 = (swz & 7) * 256, hd = (swz >> 3) & 15, b = swz >> 7;
    const int qb = q0 + w * 64;
    const int srow = w * 16 + (lane >> 2);
    const int sgr = ((lane & 3) ^ ((lane >> 3) & 3)) * 8;
    const int gsw8 = (l16 ^ ((l15 >> 1) & 3)) * 8;

    const int Nb = NbA[b];
    const int nt = (Nb + 127) >> 7;

    const u16* Khead = Kg + (size_t)b * S * D + hd * 64;
    const u16* Vthead = Vt + (size_t)(b * 16 + hd) * 64 * 2048;

    auto stage = [&](int c, int kt) {
#pragma unroll
        for (int kg = 0; kg < 2; kg++) {
            const int k0 = kt + kg * 64;
            gload16(Khead + (size_t)(k0 + srow) * D + sgr,        &Kl[c][kg][0][w * 16][0]);
            gload16(Khead + (size_t)(k0 + srow) * D + 32 + sgr,   &Kl[c][kg][1][w * 16][0]);
            gload16(Vthead + (size_t)srow * 2048 + k0 + sgr,      &Vl[c][kg][0][w * 16][0]);
            gload16(Vthead + (size_t)srow * 2048 + k0 + 32 + sgr, &Vl[c][kg][1][w * 16][0]);
        }
    };

    stage(0, 0);
    // validity vector: 1.0 for i < Nb else 0
    {
        u16x8 mv;
#pragma unroll
        for (int j = 0; j < 8; j++) mv[j] = (t * 8 + j < Nb) ? (u16)0x3F80 : (u16)0;
        *(u16x8*)&Ml[t * 8] = mv;
    }

    constexpr float QSCALE = 0.125f * 1.44269504f;
    bf16x8 aq[4][2];
#pragma unroll
    for (int qt = 0; qt < 4; qt++)
#pragma unroll
        for (int ks = 0; ks < 2; ks++) {
            const size_t qi = ((size_t)b * S + qb + qt * 16 + l15) * D +
                              hd * 64 + ks * 32 + l16 * 8;
            u16x8 raw = *(const u16x8*)&Q[qi];
            bf16x8 qv;
#pragma unroll
            for (int i = 0; i < 8; i++) qv[i] = (__bf16)(bf2f(raw[i]) * QSCALE);
            aq[qt][ks] = qv;
        }

    f32x4 acc[4][4];
    f32x4 accl[4];
#pragma unroll
    for (int qt = 0; qt < 4; qt++) {
        accl[qt] = (f32x4){0.f, 0.f, 0.f, 0.f};
#pragma unroll
        for (int dt = 0; dt < 4; dt++) acc[qt][dt] = (f32x4){0.f, 0.f, 0.f, 0.f};
    }

    __syncthreads();  // buf0 staged + Ml visible

    for (int tile = 0; tile < nt; ++tile) {
        const int c = tile & 1;
        const int cur = tile * 128;
        WAIT_LGKM0();
        hard_barrier();   // barrier1
        if (tile + 1 < nt) {
            stage(c ^ 1, cur + 128);
            WAIT_VMCNT(8);
        } else {
            WAIT_VMCNT(0);
        }
        hard_barrier();   // barrier2

#pragma unroll
        for (int kg = 0; kg < 2; kg++) {
            bf16x8 kf0[4], kf1[4], vf0[4], vf1[4];
#pragma unroll
            for (int k4 = 0; k4 < 4; k4++) {
                kf0[k4] = *(const bf16x8*)&Kl[c][kg][0][k4 * 16 + l15][gsw8];
                kf1[k4] = *(const bf16x8*)&Kl[c][kg][1][k4 * 16 + l15][gsw8];
            }
#pragma unroll
            for (int dt = 0; dt < 4; dt++) {
                vf0[dt] = *(const bf16x8*)&Vl[c][kg][0][dt * 16 + l15][gsw8];
                vf1[dt] = *(const bf16x8*)&Vl[c][kg][1][dt * 16 + l15][gsw8];
            }
            const int kbase = cur + kg * 64;
            bf16x8 mv0 = *(const bf16x8*)&Ml[kbase + l16 * 8];
            bf16x8 mv1 = *(const bf16x8*)&Ml[kbase + 32 + l16 * 8];

#pragma unroll
            for (int qt = 0; qt < 4; qt++) {
#pragma unroll
                for (int k4 = 0; k4 < 4; k4++) {
                    f32x4 z = (f32x4){0.f, 0.f, 0.f, 0.f};
                    z = __builtin_amdgcn_mfma_f32_16x16x32_bf16(kf0[k4], aq[qt][0], z, 0, 0, 0);
                    z = __builtin_amdgcn_mfma_f32_16x16x32_bf16(kf1[k4], aq[qt][1], z, 0, 0, 0);
                    u16x4 pk;
#pragma unroll
                    for (int r = 0; r < 4; r++)
                        pk[r] = f2bf(__builtin_amdgcn_exp2f(z[r]));
                    *(u16x4*)&Pl[w][l15][k4 * 16 + l16 * 4] = pk;
                }
                bf16x8 pa0 = *(const bf16x8*)&Pl[w][l15][l16 * 8];
                bf16x8 pa1 = *(const bf16x8*)&Pl[w][l15][32 + l16 * 8];
                accl[qt] = __builtin_amdgcn_mfma_f32_16x16x32_bf16(pa0, mv0, accl[qt], 0, 0, 0);
                accl[qt] = __builtin_amdgcn_mfma_f32_16x16x32_bf16(pa1, mv1, accl[qt], 0, 0, 0);
#pragma unroll
                for (int dt = 0; dt < 4; dt++) {
                    acc[qt][dt] = __builtin_amdgcn_mfma_f32_16x16x32_bf16(
                        pa0, vf0[dt], acc[qt][dt], 0, 0, 0);
                    acc[qt][dt] = __builtin_amdgcn_mfma_f32_16x16x32_bf16(
                        pa1, vf1[dt], acc[qt][dt], 0, 0, 0);
                }
            }
        }
    }

#pragma unroll
    for (int qt = 0; qt < 4; qt++) {
        f32x4 inv;
#pragma unroll
        for (int r = 0; r < 4; r++) inv[r] = 1.f / accl[qt][r];
#pragma unroll
        for (int dt = 0; dt < 4; dt++)
#pragma unroll
            for (int r = 0; r < 4; r++) {
                const int tok = qb + qt * 16 + l16 * 4 + r;
                O[((size_t)b * S + tok) * D + hd * 64 + dt * 16 + l15] =
                    f2bf(acc[qt][dt][r] * inv[r]);
            }
    }
}

extern "C" void kernel_launch(void* const* d_in, const int* in_sizes, int n_in,
                              void* d_out, int out_size, void* d_ws, size_t ws_size,
                              hipStream_t stream) {
    const float* query = (const float*)d_in[0];
    const float* key   = (const float*)d_in[1];
    const float* value = (const float*)d_in[2];
    const int*   mask  = (const int*)d_in[3];
    const float* Wq = (const float*)d_in[4];
    const float* bq = (const float*)d_in[5];
    const float* Wk = (const float*)d_in[6];
    const float* bk = (const float*)d_in[7];
    const float* Wv = (const float*)d_in[8];
    const float* bv = (const float*)d_in[9];
    const float* Wo = (const float*)d_in[10];
    const float* bo = (const float*)d_in[11];
    float* out = (float*)d_out;

    constexpr int S = 2048, D = 1024;
    constexpr size_t MSZ = (size_t)4 * S * D;   // 8388608
    constexpr size_t WSZ = (size_t)D * D;       // 1048576
    const size_t need = 4 * WSZ * 2 + 4 * MSZ * 2 + 64;
    if (ws_size < need) return;

    char* p = (char*)d_ws;
    u16* Wqb = (u16*)p; p += WSZ * 2;
    u16* Wkb = (u16*)p; p += WSZ * 2;
    u16* Wvb = (u16*)p; p += WSZ * 2;
    u16* Wob = (u16*)p; p += WSZ * 2;
    u16* Xb  = (u16*)p; p += MSZ * 2;  // attn output
    u16* Qb  = (u16*)p; p += MSZ * 2;
    u16* Kb  = (u16*)p; p += MSZ * 2;
    u16* Vtb = (u16*)p; p += MSZ * 2;  // (b,h,dk,s), masked cols zeroed
    int* NbA = (int*)p; p += 64;
    u16* Kc  = (u16*)d_out;            // compacted K (d_out scratch)
    u16* Vtc = (u16*)d_out + MSZ;      // compacted V^T

    cvt4<<<dim3(WSZ / 1024, 4), 256, 0, stream>>>(Wq, Wk, Wv, Wo,
                                                  Wqb, Wkb, Wvb, Wob, (int)WSZ);
    gemm_qkv<<<dim3(512, 1, 3), 256, 0, stream>>>(query, key, value,
                                                  Wqb, Wkb, Wvb, bq, bk, bv, mask,
                                                  Qb, Kb, Vtb, 8192, 1024, 1024);
    compactK<<<dim3(9, 4), 256, 0, stream>>>(Kb, Kc, mask);
    compactV<<<dim3(16, 4), 256, 0, stream>>>(Vtb, Vtc, mask, NbA);
    attn_fwd<<<512, 256, 0, stream>>>(Qb, Kc, Vtc, NbA, Xb);
    gemm_out<<<512, 256, 0, stream>>>(Xb, Wob, bo, out, 8192, 1024, 1024);
}

// Round 18
// 183.926 us; speedup vs baseline: 1.9883x; 1.9883x over previous
//
#include <hip/hip_runtime.h>

typedef unsigned short u16;
typedef unsigned int u32;
typedef __bf16 bf16x8 __attribute__((ext_vector_type(8)));
typedef float f32x4 __attribute__((ext_vector_type(4)));
typedef u16 u16x8 __attribute__((ext_vector_type(8)));
typedef u16 u16x4 __attribute__((ext_vector_type(4)));

typedef __attribute__((address_space(1))) const unsigned char gc_u8;
typedef __attribute__((address_space(3))) unsigned char lds_u8;

__device__ inline void gload16(const void* g, void* l) {
    __builtin_amdgcn_global_load_lds((gc_u8*)g, (lds_u8*)l, 16, 0, 0);
}
__device__ inline u16 f2bf(float f) {
    union { __bf16 h; u16 u; } c; c.h = (__bf16)f; return c.u;
}
__device__ inline float bf2f(u16 u) {
    union { u16 u[2]; float f; } c; c.u[0] = 0; c.u[1] = u; return c.f;
}
__device__ inline void hard_barrier() {
    __builtin_amdgcn_sched_barrier(0);
    __builtin_amdgcn_s_barrier();
    __builtin_amdgcn_sched_barrier(0);
}
#define WAIT_LGKM0() asm volatile("s_waitcnt lgkmcnt(0)" ::: "memory")
#define WAIT_VMCNT(n) asm volatile("s_waitcnt vmcnt(" #n ")" ::: "memory")

// ---------------- weight fp32 -> bf16 convert ----------------
__global__ __launch_bounds__(256) void cvt4(const float* __restrict__ s0,
                                            const float* __restrict__ s1,
                                            const float* __restrict__ s2,
                                            const float* __restrict__ s3,
                                            u16* __restrict__ d0, u16* __restrict__ d1,
                                            u16* __restrict__ d2, u16* __restrict__ d3,
                                            int n) {
    const int y = blockIdx.y;
    const float* src = (y == 0) ? s0 : (y == 1) ? s1 : (y == 2) ? s2 : s3;
    u16* dst = (y == 0) ? d0 : (y == 1) ? d1 : (y == 2) ? d2 : d3;
    int i = (blockIdx.x * 256 + threadIdx.x) * 4;
    if (i < n) {
        float4 f = *reinterpret_cast<const float4*>(src + i);
        u16x4 u = { f2bf(f.x), f2bf(f.y), f2bf(f.z), f2bf(f.w) };
        *reinterpret_cast<u16x4*>(dst + i) = u;
    }
}

// ---------------- zero-fill d_out scratch (compaction padding) ----------------
__global__ __launch_bounds__(256) void zero_buf(u16* __restrict__ p) {
    const size_t i = ((size_t)blockIdx.x * 256 + threadIdx.x) * 8;
    u16x8 z = {0, 0, 0, 0, 0, 0, 0, 0};
    *(u16x8*)&p[i] = z;
}

// ---------------- per-token compacted destination index (order-preserving) ----------------
// dtok[b*2048+s] = #unmasked keys before s (within batch b) if mask[s] else -1.
__global__ __launch_bounds__(256) void build_dtok(const int* __restrict__ mask,
                                                  int* __restrict__ dtok,
                                                  int* __restrict__ NbA) {
    __shared__ u32 W[64];
    __shared__ u32 Wpre[64];
    const int b = blockIdx.x, t = threadIdx.x;
    const int* mrow = mask + b * 2048;
    if (t < 64) {
        u32 wv = 0;
#pragma unroll 8
        for (int j = 0; j < 32; j++) wv |= (mrow[t * 32 + j] ? 1u : 0u) << j;
        W[t] = wv;
    }
    __syncthreads();
    if (t == 0) {
        u32 s = 0;
        for (int i = 0; i < 64; i++) { Wpre[i] = s; s += __popc(W[i]); }
        NbA[b] = (int)s;
    }
    __syncthreads();
#pragma unroll
    for (int i = 0; i < 8; i++) {
        const int s = t * 8 + i;
        const u32 word = W[s >> 5];
        const int d = (int)Wpre[s >> 5] + __popc(word & ((1u << (s & 31)) - 1u));
        dtok[b * 2048 + s] = ((word >> (s & 31)) & 1u) ? d : -1;
    }
}

// ---------------- merged QKV projection GEMM, f32-A direct, COMPACTING epilogue ----------------
// z==0: Q bf16 [tok][1024]. z==1: K compacted rows Kc[b*2048+d][1024] (masked dropped).
// z==2: V^T compacted (b,h,dk,d) (masked dropped). Pad slots pre-zeroed by zero_buf.
__global__ __launch_bounds__(256) void gemm_qkv(const float* __restrict__ Aq,
                                                const float* __restrict__ Ak,
                                                const float* __restrict__ Av,
                                                const u16* __restrict__ Bq,
                                                const u16* __restrict__ Bk,
                                                const u16* __restrict__ Bv,
                                                const float* __restrict__ bq,
                                                const float* __restrict__ bk,
                                                const float* __restrict__ bv,
                                                const int* __restrict__ dtok,
                                                u16* __restrict__ Cq,
                                                u16* __restrict__ Ck,
                                                u16* __restrict__ Cvp,
                                                int M, int N, int K) {
    __shared__ __align__(16) float Asf[2][128][32];
    __shared__ __align__(16) u16 Bs[2][128][32];
    const int z = blockIdx.z;
    const float* A = (z == 0) ? Aq : (z == 1) ? Ak : Av;
    const u16* B = (z == 0) ? Bq : (z == 1) ? Bk : Bv;
    const float* bias = (z == 0) ? bq : (z == 1) ? bk : bv;

    const int t = threadIdx.x, lane = t & 63, w = t >> 6;
    const int wr = w >> 1, wc = w & 1;
    const int l15 = lane & 15, l16 = lane >> 4;
    const int nwg = gridDim.x, ntiles = N >> 7;
    const int wg = blockIdx.x, chunk = nwg >> 3;
    const int swz = (wg & 7) * chunk + (wg >> 3);
    const int bm = (swz / ntiles) * 128, bn = (swz % ntiles) * 128;
    const int srow = w * 16 + (lane >> 2);
    const int sgr = (lane & 3) * 8;
    const int arsub = lane >> 3;
    const int agr = ((lane & 7) ^ (lane >> 3)) * 4;
    const u16* Bb = B + (size_t)bn * K;

    f32x4 acc[4][4];
#pragma unroll
    for (int i = 0; i < 4; i++)
#pragma unroll
        for (int j = 0; j < 4; j++) acc[i][j] = (f32x4){0.f, 0.f, 0.f, 0.f};

    auto stage = [&](int c, int k0) {
#pragma unroll
        for (int ch = 0; ch < 4; ch++)
            gload16(A + (size_t)(bm + ch * 32 + w * 8 + arsub) * K + k0 + agr,
                    &Asf[c][ch * 32 + w * 8][0]);
        gload16(Bb + (size_t)srow * K + k0 + sgr,        &Bs[c][w * 16][0]);
        gload16(Bb + (size_t)(64 + srow) * K + k0 + sgr, &Bs[c][64 + w * 16][0]);
    };

    stage(0, 0);
    __syncthreads();

    const int NS = K >> 5;
    for (int i = 0; i < NS; ++i) {
        const int c = i & 1;
        WAIT_LGKM0();
        hard_barrier();
        if (i + 1 < NS) {
            stage(c ^ 1, (i + 1) * 32);
            WAIT_VMCNT(6);
        } else {
            WAIT_VMCNT(0);
        }
        hard_barrier();

        const int key = l15 & 7;
        bf16x8 afr[4], bfr[4];
#pragma unroll
        for (int mi = 0; mi < 4; mi++) {
            const int rr = wr * 64 + mi * 16 + l15;
            f32x4 lo = *(const f32x4*)&Asf[c][rr][((2 * l16) ^ key) * 4];
            f32x4 hi = *(const f32x4*)&Asf[c][rr][((2 * l16 + 1) ^ key) * 4];
            bf16x8 v;
            v[0] = (__bf16)lo[0]; v[1] = (__bf16)lo[1];
            v[2] = (__bf16)lo[2]; v[3] = (__bf16)lo[3];
            v[4] = (__bf16)hi[0]; v[5] = (__bf16)hi[1];
            v[6] = (__bf16)hi[2]; v[7] = (__bf16)hi[3];
            afr[mi] = v;
        }
#pragma unroll
        for (int ni = 0; ni < 4; ni++)
            bfr[ni] = *(const bf16x8*)&Bs[c][wc * 64 + ni * 16 + l15][l16 * 8];
#pragma unroll
        for (int mi = 0; mi < 4; mi++)
#pragma unroll
            for (int ni = 0; ni < 4; ni++)
                acc[mi][ni] = __builtin_amdgcn_mfma_f32_16x16x32_bf16(
                    afr[mi], bfr[ni], acc[mi][ni], 0, 0, 0);
    }

    // compacted destination slots for this thread's 16 tokens (z>=1 only)
    int dts[4][4];
    if (z != 0) {
#pragma unroll
        for (int mi = 0; mi < 4; mi++) {
            const int r0 = bm + wr * 64 + mi * 16 + l16 * 4;
#pragma unroll
            for (int r = 0; r < 4; r++) dts[mi][r] = dtok[r0 + r];
        }
    }

#pragma unroll
    for (int ni = 0; ni < 4; ni++) {
        const int col = bn + wc * 64 + ni * 16 + l15;
        const float bv2 = bias[col];
#pragma unroll
        for (int mi = 0; mi < 4; mi++) {
            const int r0 = bm + wr * 64 + mi * 16 + l16 * 4;
            const int bb = r0 >> 11;
            if (z == 0) {
#pragma unroll
                for (int r = 0; r < 4; r++)
                    Cq[(size_t)(r0 + r) * N + col] = f2bf(acc[mi][ni][r] + bv2);
            } else if (z == 1) {  // K compacted rows
#pragma unroll
                for (int r = 0; r < 4; r++) {
                    const int d = dts[mi][r];
                    if (d >= 0)
                        Ck[((size_t)(bb * 2048 + d)) * 1024 + col] =
                            f2bf(acc[mi][ni][r] + bv2);
                }
            } else {  // V^T compacted (b,h,dk,d)
                const int hh = col >> 6, dk = col & 63;
                u16* dst = Cvp + (((size_t)(bb * 16 + hh) * 64 + dk) << 11);
#pragma unroll
                for (int r = 0; r < 4; r++) {
                    const int d = dts[mi][r];
                    if (d >= 0) dst[d] = f2bf(acc[mi][ni][r] + bv2);
                }
            }
        }
    }
}

// ---------------- out-projection GEMM (f32 out) — UNCHANGED ----------------
__global__ __launch_bounds__(256) void gemm_out(const u16* __restrict__ A,
                                                const u16* __restrict__ B,
                                                const float* __restrict__ bias,
                                                float* __restrict__ Cv,
                                                int M, int N, int K) {
    __shared__ __align__(16) u16 As[2][128][32];
    __shared__ __align__(16) u16 Bs[2][128][32];
    const int t = threadIdx.x, lane = t & 63, w = t >> 6;
    const int wr = w >> 1, wc = w & 1;
    const int l15 = lane & 15, l16 = lane >> 4;
    const int nwg = gridDim.x, ntiles = N >> 7;
    const int wg = blockIdx.x, chunk = nwg >> 3;
    const int swz = (wg & 7) * chunk + (wg >> 3);
    const int bm = (swz / ntiles) * 128, bn = (swz % ntiles) * 128;
    const int srow = w * 16 + (lane >> 2);
    const int sgr = (lane & 3) * 8;
    const u16* Ab = A + (size_t)bm * K;
    const u16* Bb = B + (size_t)bn * K;

    f32x4 acc[4][4];
#pragma unroll
    for (int i = 0; i < 4; i++)
#pragma unroll
        for (int j = 0; j < 4; j++) acc[i][j] = (f32x4){0.f, 0.f, 0.f, 0.f};

    auto stage = [&](int c, int k0) {
        gload16(Ab + (size_t)srow * K + k0 + sgr,        &As[c][w * 16][0]);
        gload16(Ab + (size_t)(64 + srow) * K + k0 + sgr, &As[c][64 + w * 16][0]);
        gload16(Bb + (size_t)srow * K + k0 + sgr,        &Bs[c][w * 16][0]);
        gload16(Bb + (size_t)(64 + srow) * K + k0 + sgr, &Bs[c][64 + w * 16][0]);
    };

    stage(0, 0);
    __syncthreads();

    const int NS = K >> 5;
    for (int i = 0; i < NS; ++i) {
        const int c = i & 1;
        WAIT_LGKM0();
        hard_barrier();
        if (i + 1 < NS) {
            stage(c ^ 1, (i + 1) * 32);
            WAIT_VMCNT(4);
        } else {
            WAIT_VMCNT(0);
        }
        hard_barrier();

        bf16x8 afr[4], bfr[4];
#pragma unroll
        for (int mi = 0; mi < 4; mi++)
            afr[mi] = *(const bf16x8*)&As[c][wr * 64 + mi * 16 + l15][l16 * 8];
#pragma unroll
        for (int ni = 0; ni < 4; ni++)
            bfr[ni] = *(const bf16x8*)&Bs[c][wc * 64 + ni * 16 + l15][l16 * 8];
#pragma unroll
        for (int mi = 0; mi < 4; mi++)
#pragma unroll
            for (int ni = 0; ni < 4; ni++)
                acc[mi][ni] = __builtin_amdgcn_mfma_f32_16x16x32_bf16(
                    afr[mi], bfr[ni], acc[mi][ni], 0, 0, 0);
    }

#pragma unroll
    for (int ni = 0; ni < 4; ni++) {
        const int col = bn + wc * 64 + ni * 16 + l15;
        const float bv = bias[col];
#pragma unroll
        for (int mi = 0; mi < 4; mi++) {
            const int r0 = bm + wr * 64 + mi * 16 + l16 * 4;
#pragma unroll
            for (int r = 0; r < 4; r++)
                Cv[(size_t)(r0 + r) * N + col] = acc[mi][ni][r] + bv;
        }
    }
}

// ---------------- flash attention over COMPACTED keys — EXACT R17 version ----------------
__global__ __launch_bounds__(256, 2) void attn_fwd(const u16* __restrict__ Q,
                                                   const u16* __restrict__ Kg,
                                                   const u16* __restrict__ Vt,
                                                   const int* __restrict__ NbA,
                                                   u16* __restrict__ O) {
    constexpr int S = 2048, D = 1024;
    __shared__ __align__(16) u16 Kl[2][2][2][64][32];
    __shared__ __align__(16) u16 Vl[2][2][2][64][32];
    __shared__ __align__(16) u16 Pl[4][16][68];
    __shared__ __align__(16) u16 Ml[2048];             // validity: i < Nb
    const int t = threadIdx.x, lane = t & 63, w = t >> 6;
    const int l15 = lane & 15, l16 = lane >> 4;
    const int wg = blockIdx.x;
    const int swz = (wg & 7) * 64 + (wg >> 3);
    const int q0 = (swz & 7) * 256, hd = (swz >> 3) & 15, b = swz >> 7;
    const int qb = q0 + w * 64;
    const int srow = w * 16 + (lane >> 2);
    const int sgr = ((lane & 3) ^ ((lane >> 3) & 3)) * 8;
    const int gsw8 = (l16 ^ ((l15 >> 1) & 3)) * 8;

    const int Nb = NbA[b];
    const int nt = (Nb + 127) >> 7;

    const u16* Khead = Kg + (size_t)b * S * D;
    const u16* Vthead = Vt + (size_t)(b * 16 + hd) * 64 * 2048;

    auto stage = [&](int c, int kt) {
#pragma unroll
        for (int kg = 0; kg < 2; kg++) {
            const int k0 = kt + kg * 64;
            gload16(Khead + (size_t)(k0 + srow) * D + hd * 64 + sgr,      &Kl[c][kg][0][w * 16][0]);
            gload16(Khead + (size_t)(k0 + srow) * D + hd * 64 + 32 + sgr, &Kl[c][kg][1][w * 16][0]);
            gload16(Vthead + (size_t)srow * 2048 + k0 + sgr,              &Vl[c][kg][0][w * 16][0]);
            gload16(Vthead + (size_t)srow * 2048 + k0 + 32 + sgr,         &Vl[c][kg][1][w * 16][0]);
        }
    };

    stage(0, 0);
    {
        u16x8 mv;
#pragma unroll
        for (int j = 0; j < 8; j++) mv[j] = (t * 8 + j < Nb) ? (u16)0x3F80 : (u16)0;
        *(u16x8*)&Ml[t * 8] = mv;
    }

    constexpr float QSCALE = 0.125f * 1.44269504f;
    bf16x8 aq[4][2];
#pragma unroll
    for (int qt = 0; qt < 4; qt++)
#pragma unroll
        for (int ks = 0; ks < 2; ks++) {
            const size_t qi = ((size_t)b * S + qb + qt * 16 + l15) * D +
                              hd * 64 + ks * 32 + l16 * 8;
            u16x8 raw = *(const u16x8*)&Q[qi];
            bf16x8 qv;
#pragma unroll
            for (int i = 0; i < 8; i++) qv[i] = (__bf16)(bf2f(raw[i]) * QSCALE);
            aq[qt][ks] = qv;
        }

    f32x4 acc[4][4];
    f32x4 accl[4];
#pragma unroll
    for (int qt = 0; qt < 4; qt++) {
        accl[qt] = (f32x4){0.f, 0.f, 0.f, 0.f};
#pragma unroll
        for (int dt = 0; dt < 4; dt++) acc[qt][dt] = (f32x4){0.f, 0.f, 0.f, 0.f};
    }

    __syncthreads();  // buf0 staged + Ml visible

    for (int tile = 0; tile < nt; ++tile) {
        const int c = tile & 1;
        const int cur = tile * 128;
        WAIT_LGKM0();
        hard_barrier();   // barrier1
        if (tile + 1 < nt) {
            stage(c ^ 1, cur + 128);
            WAIT_VMCNT(8);
        } else {
            WAIT_VMCNT(0);
        }
        hard_barrier();   // barrier2

#pragma unroll
        for (int kg = 0; kg < 2; kg++) {
            bf16x8 kf0[4], kf1[4], vf0[4], vf1[4];
#pragma unroll
            for (int k4 = 0; k4 < 4; k4++) {
                kf0[k4] = *(const bf16x8*)&Kl[c][kg][0][k4 * 16 + l15][gsw8];
                kf1[k4] = *(const bf16x8*)&Kl[c][kg][1][k4 * 16 + l15][gsw8];
            }
#pragma unroll
            for (int dt = 0; dt < 4; dt++) {
                vf0[dt] = *(const bf16x8*)&Vl[c][kg][0][dt * 16 + l15][gsw8];
                vf1[dt] = *(const bf16x8*)&Vl[c][kg][1][dt * 16 + l15][gsw8];
            }
            const int kbase = cur + kg * 64;
            bf16x8 mv0 = *(const bf16x8*)&Ml[kbase + l16 * 8];
            bf16x8 mv1 = *(const bf16x8*)&Ml[kbase + 32 + l16 * 8];

#pragma unroll
            for (int qt = 0; qt < 4; qt++) {
#pragma unroll
                for (int k4 = 0; k4 < 4; k4++) {
                    f32x4 z = (f32x4){0.f, 0.f, 0.f, 0.f};
                    z = __builtin_amdgcn_mfma_f32_16x16x32_bf16(kf0[k4], aq[qt][0], z, 0, 0, 0);
                    z = __builtin_amdgcn_mfma_f32_16x16x32_bf16(kf1[k4], aq[qt][1], z, 0, 0, 0);
                    u16x4 pk;
#pragma unroll
                    for (int r = 0; r < 4; r++)
                        pk[r] = f2bf(__builtin_amdgcn_exp2f(z[r]));
                    *(u16x4*)&Pl[w][l15][k4 * 16 + l16 * 4] = pk;
                }
                bf16x8 pa0 = *(const bf16x8*)&Pl[w][l15][l16 * 8];
                bf16x8 pa1 = *(const bf16x8*)&Pl[w][l15][32 + l16 * 8];
                accl[qt] = __builtin_amdgcn_mfma_f32_16x16x32_bf16(pa0, mv0, accl[qt], 0, 0, 0);
                accl[qt] = __builtin_amdgcn_mfma_f32_16x16x32_bf16(pa1, mv1, accl[qt], 0, 0, 0);
#pragma unroll
                for (int dt = 0; dt < 4; dt++) {
                    acc[qt][dt] = __builtin_amdgcn_mfma_f32_16x16x32_bf16(
                        pa0, vf0[dt], acc[qt][dt], 0, 0, 0);
                    acc[qt][dt] = __builtin_amdgcn_mfma_f32_16x16x32_bf16(
                        pa1, vf1[dt], acc[qt][dt], 0, 0, 0);
                }
            }
        }
    }

#pragma unroll
    for (int qt = 0; qt < 4; qt++) {
        f32x4 inv;
#pragma unroll
        for (int r = 0; r < 4; r++) inv[r] = 1.f / accl[qt][r];
#pragma unroll
        for (int dt = 0; dt < 4; dt++)
#pragma unroll
            for (int r = 0; r < 4; r++) {
                const int tok = qb + qt * 16 + l16 * 4 + r;
                O[((size_t)b * S + tok) * D + hd * 64 + dt * 16 + l15] =
                    f2bf(acc[qt][dt][r] * inv[r]);
            }
    }
}

extern "C" void kernel_launch(void* const* d_in, const int* in_sizes, int n_in,
                              void* d_out, int out_size, void* d_ws, size_t ws_size,
                              hipStream_t stream) {
    const float* query = (const float*)d_in[0];
    const float* key   = (const float*)d_in[1];
    const float* value = (const float*)d_in[2];
    const int*   mask  = (const int*)d_in[3];
    const float* Wq = (const float*)d_in[4];
    const float* bq = (const float*)d_in[5];
    const float* Wk = (const float*)d_in[6];
    const float* bk = (const float*)d_in[7];
    const float* Wv = (const float*)d_in[8];
    const float* bv = (const float*)d_in[9];
    const float* Wo = (const float*)d_in[10];
    const float* bo = (const float*)d_in[11];
    float* out = (float*)d_out;

    constexpr int S = 2048, D = 1024;
    constexpr size_t MSZ = (size_t)4 * S * D;   // 8388608
    constexpr size_t WSZ = (size_t)D * D;       // 1048576
    const size_t need = 4 * WSZ * 2 + 4 * MSZ * 2 + 8192 * 4 + 64;
    if (ws_size < need) return;

    char* p = (char*)d_ws;
    u16* Wqb = (u16*)p; p += WSZ * 2;
    u16* Wkb = (u16*)p; p += WSZ * 2;
    u16* Wvb = (u16*)p; p += WSZ * 2;
    u16* Wob = (u16*)p; p += WSZ * 2;
    u16* Xb  = (u16*)p; p += MSZ * 2;  // attn output
    u16* Qb  = (u16*)p; p += MSZ * 2;
    u16* KbUnused = (u16*)p; p += MSZ * 2;  // (layout keep; unused)
    u16* VtUnused = (u16*)p; p += MSZ * 2;  // (layout keep; unused)
    int* dtok = (int*)p; p += 8192 * 4;
    int* NbA = (int*)p; p += 64;
    (void)KbUnused; (void)VtUnused;
    u16* Kc  = (u16*)d_out;            // compacted K rows (zero-padded)
    u16* Vtc = (u16*)d_out + MSZ;      // compacted V^T (zero-padded)

    cvt4<<<dim3(WSZ / 1024, 4), 256, 0, stream>>>(Wq, Wk, Wv, Wo,
                                                  Wqb, Wkb, Wvb, Wob, (int)WSZ);
    build_dtok<<<4, 256, 0, stream>>>(mask, dtok, NbA);
    zero_buf<<<8192, 256, 0, stream>>>((u16*)d_out);   // 32 MB: Kc + Vtc pad
    gemm_qkv<<<dim3(512, 1, 3), 256, 0, stream>>>(query, key, value,
                                                  Wqb, Wkb, Wvb, bq, bk, bv, dtok,
                                                  Qb, Kc, Vtc, 8192, 1024, 1024);
    attn_fwd<<<512, 256, 0, stream>>>(Qb, Kc, Vtc, NbA, Xb);
    gemm_out<<<512, 256, 0, stream>>>(Xb, Wob, bo, out, 8192, 1024, 1024);
}

// Round 19
// 179.262 us; speedup vs baseline: 2.0400x; 1.0260x over previous
//
#include <hip/hip_runtime.h>

typedef unsigned short u16;
typedef unsigned int u32;
typedef __bf16 bf16x8 __attribute__((ext_vector_type(8)));
typedef float f32x4 __attribute__((ext_vector_type(4)));
typedef u16 u16x8 __attribute__((ext_vector_type(8)));
typedef u16 u16x4 __attribute__((ext_vector_type(4)));

typedef __attribute__((address_space(1))) const unsigned char gc_u8;
typedef __attribute__((address_space(3))) unsigned char lds_u8;

__device__ inline void gload16(const void* g, void* l) {
    __builtin_amdgcn_global_load_lds((gc_u8*)g, (lds_u8*)l, 16, 0, 0);
}
__device__ inline u16 f2bf(float f) {
    union { __bf16 h; u16 u; } c; c.h = (__bf16)f; return c.u;
}
__device__ inline float bf2f(u16 u) {
    union { u16 u[2]; float f; } c; c.u[0] = 0; c.u[1] = u; return c.f;
}
__device__ inline void hard_barrier() {
    __builtin_amdgcn_sched_barrier(0);
    __builtin_amdgcn_s_barrier();
    __builtin_amdgcn_sched_barrier(0);
}
#define WAIT_LGKM0() asm volatile("s_waitcnt lgkmcnt(0)" ::: "memory")
#define WAIT_VMCNT(n) asm volatile("s_waitcnt vmcnt(" #n ")" ::: "memory")

// ---------------- weight fp32 -> bf16 convert ----------------
__global__ __launch_bounds__(256) void cvt4(const float* __restrict__ s0,
                                            const float* __restrict__ s1,
                                            const float* __restrict__ s2,
                                            const float* __restrict__ s3,
                                            u16* __restrict__ d0, u16* __restrict__ d1,
                                            u16* __restrict__ d2, u16* __restrict__ d3,
                                            int n) {
    const int y = blockIdx.y;
    const float* src = (y == 0) ? s0 : (y == 1) ? s1 : (y == 2) ? s2 : s3;
    u16* dst = (y == 0) ? d0 : (y == 1) ? d1 : (y == 2) ? d2 : d3;
    int i = (blockIdx.x * 256 + threadIdx.x) * 4;
    if (i < n) {
        float4 f = *reinterpret_cast<const float4*>(src + i);
        u16x4 u = { f2bf(f.x), f2bf(f.y), f2bf(f.z), f2bf(f.w) };
        *reinterpret_cast<u16x4*>(dst + i) = u;
    }
}

// ---------------- per-token compacted destination index (order-preserving) ----------------
// dtok[b*2048+s]: unmasked -> d (#unmasked before s); masked with pad-slot
// Nb + rank_masked(s) < pad -> -(slot+2) (epilogue writes ZEROS there); else -1.
__global__ __launch_bounds__(256) void build_dtok(const int* __restrict__ mask,
                                                  int* __restrict__ dtok,
                                                  int* __restrict__ NbA) {
    __shared__ u32 W[64];
    __shared__ u32 Wpre[65];
    const int b = blockIdx.x, t = threadIdx.x;
    const int* mrow = mask + b * 2048;
    if (t < 64) {
        u32 wv = 0;
#pragma unroll 8
        for (int j = 0; j < 32; j++) wv |= (mrow[t * 32 + j] ? 1u : 0u) << j;
        W[t] = wv;
    }
    __syncthreads();
    if (t == 0) {
        u32 s = 0;
        for (int i = 0; i < 64; i++) { Wpre[i] = s; s += __popc(W[i]); }
        Wpre[64] = s;
        NbA[b] = (int)s;
    }
    __syncthreads();
    const int Nb = (int)Wpre[64];
    const int pad = (Nb + 127) & ~127;
#pragma unroll
    for (int i = 0; i < 8; i++) {
        const int s = t * 8 + i;
        const u32 word = W[s >> 5];
        const int pre = (int)Wpre[s >> 5] + __popc(word & ((1u << (s & 31)) - 1u));
        int v;
        if ((word >> (s & 31)) & 1u) {
            v = pre;                        // unmasked: compacted slot
        } else {
            const int slot = Nb + (s - pre);  // masked: pad-zero duty
            v = (slot < pad) ? -(slot + 2) : -1;
        }
        dtok[b * 2048 + s] = v;
    }
}

// ---------------- merged QKV projection GEMM, f32-A direct, COMPACTING epilogue ----------------
// z==0: Q bf16 [tok][1024]. z==1: K compacted rows Kc (pad rows zeroed via dtok).
// z==2: V^T compacted (b,h,dk,d) (pad slots zeroed via dtok).
// Bs uses attn-proven XOR-granule swizzle (kills the 9.4M 8-way bank conflicts).
__global__ __launch_bounds__(256) void gemm_qkv(const float* __restrict__ Aq,
                                                const float* __restrict__ Ak,
                                                const float* __restrict__ Av,
                                                const u16* __restrict__ Bq,
                                                const u16* __restrict__ Bk,
                                                const u16* __restrict__ Bv,
                                                const float* __restrict__ bq,
                                                const float* __restrict__ bk,
                                                const float* __restrict__ bv,
                                                const int* __restrict__ dtok,
                                                u16* __restrict__ Cq,
                                                u16* __restrict__ Ck,
                                                u16* __restrict__ Cvp,
                                                int M, int N, int K) {
    __shared__ __align__(16) float Asf[2][128][32];
    __shared__ __align__(16) u16 Bs[2][128][32];
    const int z = blockIdx.z;
    const float* A = (z == 0) ? Aq : (z == 1) ? Ak : Av;
    const u16* B = (z == 0) ? Bq : (z == 1) ? Bk : Bv;
    const float* bias = (z == 0) ? bq : (z == 1) ? bk : bv;

    const int t = threadIdx.x, lane = t & 63, w = t >> 6;
    const int wr = w >> 1, wc = w & 1;
    const int l15 = lane & 15, l16 = lane >> 4;
    const int nwg = gridDim.x, ntiles = N >> 7;
    const int wg = blockIdx.x, chunk = nwg >> 3;
    const int swz = (wg & 7) * chunk + (wg >> 3);
    const int bm = (swz / ntiles) * 128, bn = (swz % ntiles) * 128;
    const int srow = w * 16 + (lane >> 2);
    const int sgrB = ((lane & 3) ^ ((lane >> 3) & 3)) * 8;  // swizzled bf16 source granule
    const int gswB = (l16 ^ ((l15 >> 1) & 3)) * 8;          // swizzled bf16 read granule
    const int arsub = lane >> 3;
    const int agr = ((lane & 7) ^ (lane >> 3)) * 4;         // f32 source granule (R13-proven)
    const u16* Bb = B + (size_t)bn * K;

    f32x4 acc[4][4];
#pragma unroll
    for (int i = 0; i < 4; i++)
#pragma unroll
        for (int j = 0; j < 4; j++) acc[i][j] = (f32x4){0.f, 0.f, 0.f, 0.f};

    auto stage = [&](int c, int k0) {
#pragma unroll
        for (int ch = 0; ch < 4; ch++)
            gload16(A + (size_t)(bm + ch * 32 + w * 8 + arsub) * K + k0 + agr,
                    &Asf[c][ch * 32 + w * 8][0]);
        gload16(Bb + (size_t)srow * K + k0 + sgrB,        &Bs[c][w * 16][0]);
        gload16(Bb + (size_t)(64 + srow) * K + k0 + sgrB, &Bs[c][64 + w * 16][0]);
    };

    stage(0, 0);
    __syncthreads();

    const int NS = K >> 5;
    for (int i = 0; i < NS; ++i) {
        const int c = i & 1;
        WAIT_LGKM0();
        hard_barrier();
        if (i + 1 < NS) {
            stage(c ^ 1, (i + 1) * 32);
            WAIT_VMCNT(6);
        } else {
            WAIT_VMCNT(0);
        }
        hard_barrier();

        const int key = l15 & 7;
        bf16x8 afr[4], bfr[4];
#pragma unroll
        for (int mi = 0; mi < 4; mi++) {
            const int rr = wr * 64 + mi * 16 + l15;
            f32x4 lo = *(const f32x4*)&Asf[c][rr][((2 * l16) ^ key) * 4];
            f32x4 hi = *(const f32x4*)&Asf[c][rr][((2 * l16 + 1) ^ key) * 4];
            bf16x8 v;
            v[0] = (__bf16)lo[0]; v[1] = (__bf16)lo[1];
            v[2] = (__bf16)lo[2]; v[3] = (__bf16)lo[3];
            v[4] = (__bf16)hi[0]; v[5] = (__bf16)hi[1];
            v[6] = (__bf16)hi[2]; v[7] = (__bf16)hi[3];
            afr[mi] = v;
        }
#pragma unroll
        for (int ni = 0; ni < 4; ni++)
            bfr[ni] = *(const bf16x8*)&Bs[c][wc * 64 + ni * 16 + l15][gswB];
#pragma unroll
        for (int mi = 0; mi < 4; mi++)
#pragma unroll
            for (int ni = 0; ni < 4; ni++)
                acc[mi][ni] = __builtin_amdgcn_mfma_f32_16x16x32_bf16(
                    afr[mi], bfr[ni], acc[mi][ni], 0, 0, 0);
    }

    // compacted destination slots for this thread's 16 tokens (z>=1 only)
    int dts[4][4];
    if (z != 0) {
#pragma unroll
        for (int mi = 0; mi < 4; mi++) {
            const int r0 = bm + wr * 64 + mi * 16 + l16 * 4;
#pragma unroll
            for (int r = 0; r < 4; r++) dts[mi][r] = dtok[r0 + r];
        }
    }

#pragma unroll
    for (int ni = 0; ni < 4; ni++) {
        const int col = bn + wc * 64 + ni * 16 + l15;
        const float bv2 = bias[col];
#pragma unroll
        for (int mi = 0; mi < 4; mi++) {
            const int r0 = bm + wr * 64 + mi * 16 + l16 * 4;
            const int bb = r0 >> 11;
            if (z == 0) {
#pragma unroll
                for (int r = 0; r < 4; r++)
                    Cq[(size_t)(r0 + r) * N + col] = f2bf(acc[mi][ni][r] + bv2);
            } else if (z == 1) {  // K compacted rows (+ pad-zero duty)
#pragma unroll
                for (int r = 0; r < 4; r++) {
                    const int d = dts[mi][r];
                    if (d >= 0)
                        Ck[((size_t)(bb * 2048 + d)) * 1024 + col] =
                            f2bf(acc[mi][ni][r] + bv2);
                    else if (d != -1)
                        Ck[((size_t)(bb * 2048 + (-d - 2))) * 1024 + col] = 0;
                }
            } else {  // V^T compacted (b,h,dk,d) (+ pad-zero duty)
                const int hh = col >> 6, dk = col & 63;
                u16* dst = Cvp + (((size_t)(bb * 16 + hh) * 64 + dk) << 11);
#pragma unroll
                for (int r = 0; r < 4; r++) {
                    const int d = dts[mi][r];
                    if (d >= 0) dst[d] = f2bf(acc[mi][ni][r] + bv2);
                    else if (d != -1) dst[-d - 2] = 0;
                }
            }
        }
    }
}

// ---------------- out-projection GEMM (f32 out), swizzled LDS ----------------
__global__ __launch_bounds__(256) void gemm_out(const u16* __restrict__ A,
                                                const u16* __restrict__ B,
                                                const float* __restrict__ bias,
                                                float* __restrict__ Cv,
                                                int M, int N, int K) {
    __shared__ __align__(16) u16 As[2][128][32];
    __shared__ __align__(16) u16 Bs[2][128][32];
    const int t = threadIdx.x, lane = t & 63, w = t >> 6;
    const int wr = w >> 1, wc = w & 1;
    const int l15 = lane & 15, l16 = lane >> 4;
    const int nwg = gridDim.x, ntiles = N >> 7;
    const int wg = blockIdx.x, chunk = nwg >> 3;
    const int swz = (wg & 7) * chunk + (wg >> 3);
    const int bm = (swz / ntiles) * 128, bn = (swz % ntiles) * 128;
    const int srow = w * 16 + (lane >> 2);
    const int sgrB = ((lane & 3) ^ ((lane >> 3) & 3)) * 8;  // swizzled source granule
    const int gswB = (l16 ^ ((l15 >> 1) & 3)) * 8;          // swizzled read granule
    const u16* Ab = A + (size_t)bm * K;
    const u16* Bb = B + (size_t)bn * K;

    f32x4 acc[4][4];
#pragma unroll
    for (int i = 0; i < 4; i++)
#pragma unroll
        for (int j = 0; j < 4; j++) acc[i][j] = (f32x4){0.f, 0.f, 0.f, 0.f};

    auto stage = [&](int c, int k0) {
        gload16(Ab + (size_t)srow * K + k0 + sgrB,        &As[c][w * 16][0]);
        gload16(Ab + (size_t)(64 + srow) * K + k0 + sgrB, &As[c][64 + w * 16][0]);
        gload16(Bb + (size_t)srow * K + k0 + sgrB,        &Bs[c][w * 16][0]);
        gload16(Bb + (size_t)(64 + srow) * K + k0 + sgrB, &Bs[c][64 + w * 16][0]);
    };

    stage(0, 0);
    __syncthreads();

    const int NS = K >> 5;
    for (int i = 0; i < NS; ++i) {
        const int c = i & 1;
        WAIT_LGKM0();
        hard_barrier();
        if (i + 1 < NS) {
            stage(c ^ 1, (i + 1) * 32);
            WAIT_VMCNT(4);
        } else {
            WAIT_VMCNT(0);
        }
        hard_barrier();

        bf16x8 afr[4], bfr[4];
#pragma unroll
        for (int mi = 0; mi < 4; mi++)
            afr[mi] = *(const bf16x8*)&As[c][wr * 64 + mi * 16 + l15][gswB];
#pragma unroll
        for (int ni = 0; ni < 4; ni++)
            bfr[ni] = *(const bf16x8*)&Bs[c][wc * 64 + ni * 16 + l15][gswB];
#pragma unroll
        for (int mi = 0; mi < 4; mi++)
#pragma unroll
            for (int ni = 0; ni < 4; ni++)
                acc[mi][ni] = __builtin_amdgcn_mfma_f32_16x16x32_bf16(
                    afr[mi], bfr[ni], acc[mi][ni], 0, 0, 0);
    }

#pragma unroll
    for (int ni = 0; ni < 4; ni++) {
        const int col = bn + wc * 64 + ni * 16 + l15;
        const float bv = bias[col];
#pragma unroll
        for (int mi = 0; mi < 4; mi++) {
            const int r0 = bm + wr * 64 + mi * 16 + l16 * 4;
#pragma unroll
            for (int r = 0; r < 4; r++)
                Cv[(size_t)(r0 + r) * N + col] = acc[mi][ni][r] + bv;
        }
    }
}

// ---------------- flash attention over COMPACTED keys — EXACT R18 version ----------------
__global__ __launch_bounds__(256, 2) void attn_fwd(const u16* __restrict__ Q,
                                                   const u16* __restrict__ Kg,
                                                   const u16* __restrict__ Vt,
                                                   const int* __restrict__ NbA,
                                                   u16* __restrict__ O) {
    constexpr int S = 2048, D = 1024;
    __shared__ __align__(16) u16 Kl[2][2][2][64][32];
    __shared__ __align__(16) u16 Vl[2][2][2][64][32];
    __shared__ __align__(16) u16 Pl[4][16][68];
    __shared__ __align__(16) u16 Ml[2048];
    const int t = threadIdx.x, lane = t & 63, w = t >> 6;
    const int l15 = lane & 15, l16 = lane >> 4;
    const int wg = blockIdx.x;
    const int swz = (wg & 7) * 64 + (wg >> 3);
    const int q0 = (swz & 7) * 256, hd = (swz >> 3) & 15, b = swz >> 7;
    const int qb = q0 + w * 64;
    const int srow = w * 16 + (lane >> 2);
    const int sgr = ((lane & 3) ^ ((lane >> 3) & 3)) * 8;
    const int gsw8 = (l16 ^ ((l15 >> 1) & 3)) * 8;

    const int Nb = NbA[b];
    const int nt = (Nb + 127) >> 7;

    const u16* Khead = Kg + (size_t)b * S * D;
    const u16* Vthead = Vt + (size_t)(b * 16 + hd) * 64 * 2048;

    auto stage = [&](int c, int kt) {
#pragma unroll
        for (int kg = 0; kg < 2; kg++) {
            const int k0 = kt + kg * 64;
            gload16(Khead + (size_t)(k0 + srow) * D + hd * 64 + sgr,      &Kl[c][kg][0][w * 16][0]);
            gload16(Khead + (size_t)(k0 + srow) * D + hd * 64 + 32 + sgr, &Kl[c][kg][1][w * 16][0]);
            gload16(Vthead + (size_t)srow * 2048 + k0 + sgr,              &Vl[c][kg][0][w * 16][0]);
            gload16(Vthead + (size_t)srow * 2048 + k0 + 32 + sgr,         &Vl[c][kg][1][w * 16][0]);
        }
    };

    stage(0, 0);
    {
        u16x8 mv;
#pragma unroll
        for (int j = 0; j < 8; j++) mv[j] = (t * 8 + j < Nb) ? (u16)0x3F80 : (u16)0;
        *(u16x8*)&Ml[t * 8] = mv;
    }

    constexpr float QSCALE = 0.125f * 1.44269504f;
    bf16x8 aq[4][2];
#pragma unroll
    for (int qt = 0; qt < 4; qt++)
#pragma unroll
        for (int ks = 0; ks < 2; ks++) {
            const size_t qi = ((size_t)b * S + qb + qt * 16 + l15) * D +
                              hd * 64 + ks * 32 + l16 * 8;
            u16x8 raw = *(const u16x8*)&Q[qi];
            bf16x8 qv;
#pragma unroll
            for (int i = 0; i < 8; i++) qv[i] = (__bf16)(bf2f(raw[i]) * QSCALE);
            aq[qt][ks] = qv;
        }

    f32x4 acc[4][4];
    f32x4 accl[4];
#pragma unroll
    for (int qt = 0; qt < 4; qt++) {
        accl[qt] = (f32x4){0.f, 0.f, 0.f, 0.f};
#pragma unroll
        for (int dt = 0; dt < 4; dt++) acc[qt][dt] = (f32x4){0.f, 0.f, 0.f, 0.f};
    }

    __syncthreads();  // buf0 staged + Ml visible

    for (int tile = 0; tile < nt; ++tile) {
        const int c = tile & 1;
        const int cur = tile * 128;
        WAIT_LGKM0();
        hard_barrier();   // barrier1
        if (tile + 1 < nt) {
            stage(c ^ 1, cur + 128);
            WAIT_VMCNT(8);
        } else {
            WAIT_VMCNT(0);
        }
        hard_barrier();   // barrier2

#pragma unroll
        for (int kg = 0; kg < 2; kg++) {
            bf16x8 kf0[4], kf1[4], vf0[4], vf1[4];
#pragma unroll
            for (int k4 = 0; k4 < 4; k4++) {
                kf0[k4] = *(const bf16x8*)&Kl[c][kg][0][k4 * 16 + l15][gsw8];
                kf1[k4] = *(const bf16x8*)&Kl[c][kg][1][k4 * 16 + l15][gsw8];
            }
#pragma unroll
            for (int dt = 0; dt < 4; dt++) {
                vf0[dt] = *(const bf16x8*)&Vl[c][kg][0][dt * 16 + l15][gsw8];
                vf1[dt] = *(const bf16x8*)&Vl[c][kg][1][dt * 16 + l15][gsw8];
            }
            const int kbase = cur + kg * 64;
            bf16x8 mv0 = *(const bf16x8*)&Ml[kbase + l16 * 8];
            bf16x8 mv1 = *(const bf16x8*)&Ml[kbase + 32 + l16 * 8];

#pragma unroll
            for (int qt = 0; qt < 4; qt++) {
#pragma unroll
                for (int k4 = 0; k4 < 4; k4++) {
                    f32x4 z = (f32x4){0.f, 0.f, 0.f, 0.f};
                    z = __builtin_amdgcn_mfma_f32_16x16x32_bf16(kf0[k4], aq[qt][0], z, 0, 0, 0);
                    z = __builtin_amdgcn_mfma_f32_16x16x32_bf16(kf1[k4], aq[qt][1], z, 0, 0, 0);
                    u16x4 pk;
#pragma unroll
                    for (int r = 0; r < 4; r++)
                        pk[r] = f2bf(__builtin_amdgcn_exp2f(z[r]));
                    *(u16x4*)&Pl[w][l15][k4 * 16 + l16 * 4] = pk;
                }
                bf16x8 pa0 = *(const bf16x8*)&Pl[w][l15][l16 * 8];
                bf16x8 pa1 = *(const bf16x8*)&Pl[w][l15][32 + l16 * 8];
                accl[qt] = __builtin_amdgcn_mfma_f32_16x16x32_bf16(pa0, mv0, accl[qt], 0, 0, 0);
                accl[qt] = __builtin_amdgcn_mfma_f32_16x16x32_bf16(pa1, mv1, accl[qt], 0, 0, 0);
#pragma unroll
                for (int dt = 0; dt < 4; dt++) {
                    acc[qt][dt] = __builtin_amdgcn_mfma_f32_16x16x32_bf16(
                        pa0, vf0[dt], acc[qt][dt], 0, 0, 0);
                    acc[qt][dt] = __builtin_amdgcn_mfma_f32_16x16x32_bf16(
                        pa1, vf1[dt], acc[qt][dt], 0, 0, 0);
                }
            }
        }
    }

#pragma unroll
    for (int qt = 0; qt < 4; qt++) {
        f32x4 inv;
#pragma unroll
        for (int r = 0; r < 4; r++) inv[r] = 1.f / accl[qt][r];
#pragma unroll
        for (int dt = 0; dt < 4; dt++)
#pragma unroll
            for (int r = 0; r < 4; r++) {
                const int tok = qb + qt * 16 + l16 * 4 + r;
                O[((size_t)b * S + tok) * D + hd * 64 + dt * 16 + l15] =
                    f2bf(acc[qt][dt][r] * inv[r]);
            }
    }
}

extern "C" void kernel_launch(void* const* d_in, const int* in_sizes, int n_in,
                              void* d_out, int out_size, void* d_ws, size_t ws_size,
                              hipStream_t stream) {
    const float* query = (const float*)d_in[0];
    const float* key   = (const float*)d_in[1];
    const float* value = (const float*)d_in[2];
    const int*   mask  = (const int*)d_in[3];
    const float* Wq = (const float*)d_in[4];
    const float* bq = (const float*)d_in[5];
    const float* Wk = (const float*)d_in[6];
    const float* bk = (const float*)d_in[7];
    const float* Wv = (const float*)d_in[8];
    const float* bv = (const float*)d_in[9];
    const float* Wo = (const float*)d_in[10];
    const float* bo = (const float*)d_in[11];
    float* out = (float*)d_out;

    constexpr int S = 2048, D = 1024;
    constexpr size_t MSZ = (size_t)4 * S * D;   // 8388608
    constexpr size_t WSZ = (size_t)D * D;       // 1048576
    const size_t need = 4 * WSZ * 2 + 2 * MSZ * 2 + 8192 * 4 + 64;
    if (ws_size < need) return;

    char* p = (char*)d_ws;
    u16* Wqb = (u16*)p; p += WSZ * 2;
    u16* Wkb = (u16*)p; p += WSZ * 2;
    u16* Wvb = (u16*)p; p += WSZ * 2;
    u16* Wob = (u16*)p; p += WSZ * 2;
    u16* Xb  = (u16*)p; p += MSZ * 2;  // attn output
    u16* Qb  = (u16*)p; p += MSZ * 2;
    int* dtok = (int*)p; p += 8192 * 4;
    int* NbA = (int*)p; p += 64;
    u16* Kc  = (u16*)d_out;            // compacted K rows (pad rows zeroed in-epilogue)
    u16* Vtc = (u16*)d_out + MSZ;      // compacted V^T (pad slots zeroed in-epilogue)

    cvt4<<<dim3(WSZ / 1024, 4), 256, 0, stream>>>(Wq, Wk, Wv, Wo,
                                                  Wqb, Wkb, Wvb, Wob, (int)WSZ);
    build_dtok<<<4, 256, 0, stream>>>(mask, dtok, NbA);
    gemm_qkv<<<dim3(512, 1, 3), 256, 0, stream>>>(query, key, value,
                                                  Wqb, Wkb, Wvb, bq, bk, bv, dtok,
                                                  Qb, Kc, Vtc, 8192, 1024, 1024);
    attn_fwd<<<512, 256, 0, stream>>>(Qb, Kc, Vtc, NbA, Xb);
    gemm_out<<<512, 256, 0, stream>>>(Xb, Wob, bo, out, 8192, 1024, 1024);
}